// Round 1
// baseline (388.593 us; speedup 1.0000x reference)
//
#include <hip/hip_runtime.h>
#include <math.h>

#define NPTS  500000
#define NB    256      // batch / queries
#define DIM   34
#define TOPK  10
#define CAP   2048     // candidate buffer per query
#define SBLK  256      // sample kernel blocks
#define SPER  64       // sample points per block -> sample = 16384
#define MBLK  1024     // main scan blocks
#define CHUNK ((NPTS + MBLK - 1) / MBLK)   // 489

// --- bitwise-identical score pieces used by k_sample and k_scan -------------
__device__ __forceinline__ float norm34(const float* __restrict__ r) {
    float a0 = 0.f, a1 = 0.f, a2 = 0.f, a3 = 0.f;
#pragma unroll
    for (int d = 0; d < 32; d += 4) {
        a0 = fmaf(r[d + 0], r[d + 0], a0);
        a1 = fmaf(r[d + 1], r[d + 1], a1);
        a2 = fmaf(r[d + 2], r[d + 2], a2);
        a3 = fmaf(r[d + 3], r[d + 3], a3);
    }
    a0 = fmaf(r[32], r[32], a0);
    a1 = fmaf(r[33], r[33], a1);
    return (a0 + a1) + (a2 + a3);
}

__device__ __forceinline__ float dot34(const float* __restrict__ r, const float* q) {
    float a0 = 0.f, a1 = 0.f, a2 = 0.f, a3 = 0.f;
#pragma unroll
    for (int d = 0; d < 32; d += 4) {
        a0 = fmaf(r[d + 0], q[d + 0], a0);
        a1 = fmaf(r[d + 1], q[d + 1], a1);
        a2 = fmaf(r[d + 2], q[d + 2], a2);
        a3 = fmaf(r[d + 3], q[d + 3], a3);
    }
    a0 = fmaf(r[32], q[32], a0);
    a1 = fmaf(r[33], q[33], a1);
    return (a0 + a1) + (a2 + a3);
}

__device__ __forceinline__ void load_q(const float* __restrict__ obs,
                                       const float* __restrict__ act, int b, float* q) {
#pragma unroll
    for (int d = 0; d < 32; ++d) q[d] = obs[b * 32 + d];
    q[32] = act[b * 2 + 0];
    q[33] = act[b * 2 + 1];
}

// --- kernel 0a: per-(query, 64-point slice) minimum of s --------------------
__global__ __launch_bounds__(256, 4) void k_sample(const float* __restrict__ obs,
                                                   const float* __restrict__ act,
                                                   const float* __restrict__ msa,
                                                   float* __restrict__ minima) {
    __shared__ float mn[SPER];
    const int g = blockIdx.x, t = threadIdx.x;
    const int base = g * SPER;
    if (t < SPER) mn[t] = norm34(msa + (size_t)(base + t) * DIM);
    __syncthreads();
    float q[DIM];
    load_q(obs, act, t, q);
    float best = __builtin_inff();
    for (int j = 0; j < SPER; ++j) {              // j uniform across block
        const float* row = msa + (size_t)(base + j) * DIM;
        float s = fmaf(-2.f, dot34(row, q), mn[j]);
        best = fminf(best, s);
    }
    minima[g * NB + t] = best;                    // coalesced
}

// --- kernel 0b: tau_b = 10th smallest of the 256 slice minima; zero counts --
__global__ __launch_bounds__(64) void k_tau(const float* __restrict__ minima,
                                            float* __restrict__ tau,
                                            int* __restrict__ count) {
    const int b = blockIdx.x, lane = threadIdx.x;
    if (lane == 0) count[b] = 0;
    float v[4];
#pragma unroll
    for (int k = 0; k < 4; ++k) v[k] = minima[(lane + 64 * k) * NB + b];
    float last = 0.f;
    for (int r = 0; r < TOPK; ++r) {
        float lm = v[0]; int la = 0;
#pragma unroll
        for (int k = 1; k < 4; ++k) { if (v[k] < lm) { lm = v[k]; la = k; } }
        float wm = lm;
        for (int off = 32; off; off >>= 1) wm = fminf(wm, __shfl_xor(wm, off));
        unsigned long long msk = __ballot(lm == wm);
        int first = (int)__builtin_ctzll(msk);
        if (lane == first) {
            // consume exactly one instance of the wave minimum
#pragma unroll
            for (int k = 0; k < 4; ++k) { if (k == la) v[k] = __builtin_inff(); }
        }
        last = wm;
    }
    if (lane == 0) tau[b] = last;
}

// --- kernel 1: full scan, append candidates with s <= tau -------------------
__global__ __launch_bounds__(256, 4) void k_scan(const float* __restrict__ obs,
                                                 const float* __restrict__ act,
                                                 const float* __restrict__ msa,
                                                 const float* __restrict__ tau_arr,
                                                 int* __restrict__ count,
                                                 float* __restrict__ cand_s,
                                                 int* __restrict__ cand_i) {
    __shared__ float mn[CHUNK];
    const int g = blockIdx.x, t = threadIdx.x;
    const int lo = g * CHUNK;
    const int hi = (lo + CHUNK < NPTS) ? lo + CHUNK : NPTS;
    const int n = hi - lo;
    if (n <= 0) return;                           // uniform per block
    for (int j = t; j < n; j += 256) mn[j] = norm34(msa + (size_t)(lo + j) * DIM);
    __syncthreads();
    float q[DIM];
    load_q(obs, act, t, q);
    const float tau = tau_arr[t];
    for (int j = 0; j < n; ++j) {                 // j uniform: row loads scalarizable
        const float* row = msa + (size_t)(lo + j) * DIM;
        float s = fmaf(-2.f, dot34(row, q), mn[j]);
        if (s <= tau) {                           // rare (~0.06% per lane)
            int slot = atomicAdd(count + t, 1);
            if (slot < CAP) {
                cand_s[(size_t)t * CAP + slot] = s;
                cand_i[(size_t)t * CAP + slot] = lo + j;
            }
        }
    }
}

// --- kernel 2: exact top-10 (lexicographic (s, idx)), softmax, output -------
__global__ __launch_bounds__(256) void k_final(float* __restrict__ cand_s,
                                               int* __restrict__ cand_i,
                                               const int* __restrict__ count,
                                               const float* __restrict__ memQ,
                                               float* __restrict__ out) {
    const int b = blockIdx.x, t = threadIdx.x;
    const int lane = t & 63, wid = t >> 6;
    __shared__ float rs[4];
    __shared__ int   ri[4];
    __shared__ float sel_s[TOPK];
    __shared__ int   sel_i[TOPK];
    float* cs = cand_s + (size_t)b * CAP;
    int*   ci = cand_i + (size_t)b * CAP;
    int cnt = count[b];
    if (cnt > CAP) cnt = CAP;
    for (int k = 0; k < TOPK; ++k) {
        float bs = __builtin_inff();
        int   bi = 0x7fffffff;
        for (int j = t; j < cnt; j += 256) {
            float s = cs[j]; int i = ci[j];
            if (s < bs || (s == bs && i < bi)) { bs = s; bi = i; }
        }
        for (int off = 32; off; off >>= 1) {      // wave lexicographic argmin
            float s2 = __shfl_down(bs, off);
            int   i2 = __shfl_down(bi, off);
            if (s2 < bs || (s2 == bs && i2 < bi)) { bs = s2; bi = i2; }
        }
        if (lane == 0) { rs[wid] = bs; ri[wid] = bi; }
        __syncthreads();
        if (t == 0) {
            float fs = rs[0]; int fi = ri[0];
#pragma unroll
            for (int w = 1; w < 4; ++w) {
                if (rs[w] < fs || (rs[w] == fs && ri[w] < fi)) { fs = rs[w]; fi = ri[w]; }
            }
            sel_s[k] = fs; sel_i[k] = fi;
        }
        __syncthreads();
        const int win = sel_i[k];
        for (int j = t; j < cnt; j += 256) {      // consume winner
            if (ci[j] == win) cs[j] = __builtin_inff();
        }
        __syncthreads();
    }
    if (t == 0) {
        // sel_s ascending; weights = softmax(d2) == softmax(s) (shift-invariant)
        float m = sel_s[TOPK - 1];
        float wsum = 0.f, acc = 0.f;
#pragma unroll
        for (int k = 0; k < TOPK; ++k) {
            if (sel_i[k] == 0x7fffffff) continue; // paranoia; cnt>=10 guaranteed
            float w = expf(sel_s[k] - m);
            wsum += w;
            acc = fmaf(w, memQ[sel_i[k]], acc);
        }
        out[b] = acc / wsum;
    }
}

extern "C" void kernel_launch(void* const* d_in, const int* in_sizes, int n_in,
                              void* d_out, int out_size, void* d_ws, size_t ws_size,
                              hipStream_t stream) {
    const float* obs = (const float*)d_in[0];   // [256,32]
    const float* act = (const float*)d_in[1];   // [256,2]
    const float* msa = (const float*)d_in[2];   // [500000,34]
    const float* mq  = (const float*)d_in[3];   // [500000,1]
    float* out = (float*)d_out;                 // [256]

    float* wsf    = (float*)d_ws;
    float* tau    = wsf;                                  // 256 f
    int*   count  = (int*)(wsf + NB);                     // 256 i
    float* minima = wsf + 2 * NB;                         // 256*256 f
    float* cand_s = wsf + 2 * NB + SBLK * NB;             // 256*CAP f
    int*   cand_i = (int*)(cand_s + (size_t)NB * CAP);    // 256*CAP i
    // total ws use: (512 + 65536 + 2*256*2048) * 4 B ~= 4.25 MB

    k_sample<<<SBLK, NB, 0, stream>>>(obs, act, msa, minima);
    k_tau   <<<NB, 64, 0, stream>>>(minima, tau, count);
    k_scan  <<<MBLK, NB, 0, stream>>>(obs, act, msa, tau, count, cand_s, cand_i);
    k_final <<<NB, NB, 0, stream>>>(cand_s, cand_i, count, mq, out);
}